// Round 14
// baseline (544.287 us; speedup 1.0000x reference)
//
#include <hip/hip_runtime.h>
#include <hip/hip_bf16.h>
#include <math.h>

#define BB 2
#define DIM 384
#define HID 384
#define HW 65536

typedef short s16x8 __attribute__((ext_vector_type(8)));
typedef short s16x4 __attribute__((ext_vector_type(4)));
typedef __bf16 bf16x8 __attribute__((ext_vector_type(8)));
typedef float f32x4 __attribute__((ext_vector_type(4)));

__device__ inline short f2b(float f) {
    __hip_bfloat16 h = __float2bfloat16(f);
    return __builtin_bit_cast(short, h);
}
__device__ inline float b2f(short s) {
    return __bfloat162float(__builtin_bit_cast(__hip_bfloat16, s));
}

// Abramowitz-Stegun 7.1.26 erf approximation, |err| <= 1.5e-7 absolute.
__device__ inline float erf_fast(float x) {
    float ax = fabsf(x);
    float t = __builtin_amdgcn_rcpf(fmaf(0.3275911f, ax, 1.f));
    float p = fmaf(t, 1.061405429f, -1.453152027f);
    p = fmaf(t, p, 1.421413741f);
    p = fmaf(t, p, -0.284496736f);
    p = fmaf(t, p, 0.254829592f);
    p = p * t;
    float e = __expf(-ax * ax);
    float r = fmaf(-p, e, 1.f);
    return copysignf(r, x);
}

__device__ inline void gl_lds16(const short* g, short* l) {
    __builtin_amdgcn_global_load_lds(
        (const __attribute__((address_space(1))) unsigned int*)g,
        (__attribute__((address_space(3))) unsigned int*)l, 16, 0, 0);
}

// ---------------------------------------------------------------------------
// x [b][c][hw] fp32 -> Xt PATCH-MAJOR [b][pid*64+uv][384] bf16.
// Also absorbs the prep work (wbin/wbout cvt, Dtc, Rb) in its first 976
// (y==0,z==0) blocks — 249856 = 976*256 items exactly; saves a launch.
// ---------------------------------------------------------------------------
__global__ __launch_bounds__(256) void k_cvtx(const float* __restrict__ X, short* __restrict__ Xt,
                                              const float* __restrict__ w_in,
                                              const float* __restrict__ w_out,
                                              const float* __restrict__ F,
                                              short* __restrict__ wbin, short* __restrict__ wbout,
                                              float* __restrict__ Dtc, short* __restrict__ Rb) {
    int hw0 = blockIdx.x * 64, c0 = blockIdx.y * 64, b = blockIdx.z;
    __shared__ __align__(16) short S[64 * 64];
    int t = threadIdx.x;
    if (blockIdx.y == 0 && blockIdx.z == 0 && blockIdx.x < 976) {
        int i = blockIdx.x * 256 + t;
        if (i < 147456) { wbin[i] = f2b(w_in[i]); }
        else if ((i -= 147456) < 73728) { wbout[i] = f2b(w_out[i]); }
        else if ((i -= 73728) < 24576) {
            int c = i >> 6, j = i & 63;
            int a = j >> 3, q = j & 7;
            float d;
            if (q >= 1 && q <= 3)
                d = F[c * 40 + a * 5 + q];
            else if (q >= 5)
                d = F[c * 40 + ((8 - a) & 7) * 5 + (8 - q)];
            else
                d = 0.5f * (F[c * 40 + a * 5 + q] + F[c * 40 + ((8 - a) & 7) * 5 + q]);
            Dtc[i] = d * (1.f / 64.f);
        } else {
            i -= 24576;   // < 4096
            int j = i >> 6, k = i & 63;
            const float cas[8] = {1.f, 1.41421356237f, 1.f, 0.f, -1.f, -1.41421356237f, -1.f, 0.f};
            int tt = ((j >> 3) * (k >> 3) + (j & 7) * (k & 7)) & 7;
            Rb[i] = f2b(cas[tt]);
        }
    }
    const float* Xb = X + ((size_t)(b * DIM) << 16);
    short* Xtb = Xt + (size_t)b * HW * DIM;
#pragma unroll
    for (int p = 0; p < 2; ++p) {
        int row = p * 32 + (t >> 3), sb = t & 7;
        const float* src = &Xb[((size_t)(c0 + row) << 16) + hw0 + sb * 8];
        float4 a = *(const float4*)src;
        float4 bq = *(const float4*)(src + 4);
        s16x8 v;
        v[0] = f2b(a.x);  v[1] = f2b(a.y);  v[2] = f2b(a.z);  v[3] = f2b(a.w);
        v[4] = f2b(bq.x); v[5] = f2b(bq.y); v[6] = f2b(bq.z); v[7] = f2b(bq.w);
        *(s16x8*)&S[row * 64 + ((sb ^ (row >> 3)) << 3)] = v;
    }
    __syncthreads();
    int h = hw0 >> 8, wb0 = hw0 & 255;
#pragma unroll
    for (int p = 0; p < 2; ++p) {
        int row = p * 32 + (t >> 3), ch = t & 7;
        s16x8 v;
#pragma unroll
        for (int j = 0; j < 8; ++j)
            v[j] = S[(ch * 8 + j) * 64 + (row ^ (ch << 3))];
        int wv = wb0 + row;
        int rowp = (((h >> 3) << 5) + (wv >> 3)) * 64 + ((h & 7) << 3) + (wv & 7);
        *(s16x8*)&Xtb[(size_t)rowp * DIM + c0 + ch * 8] = v;
    }
}

// ---------------------------------------------------------------------------
// Fused GEMM1 + Hartley circular conv. Counted-vmcnt pipeline:
// X (streaming) = 3 buffers issued BEFORE the barrier; W (L2-hot weights) =
// 2 buffers issued AFTER the barrier (race-free by barrier ordering).
// LDS = 40 KB (4 blocks/CU): Hartley R is loaded into REGISTERS at the
// EPILOGUE (after the main loop; in-loop asm memory fences prevent LICM
// hoisting) — R10's spill came from launch_bounds(256,4), not reg-R itself.
// ---------------------------------------------------------------------------
__global__ __launch_bounds__(256) void k_gemm1c(const short* __restrict__ W,
                                                const short* __restrict__ Xt,
                                                const short* __restrict__ Rb,
                                                const float* __restrict__ Dtc,
                                                short* __restrict__ T) {
    // shorts: X bufs @0,4096,8192 | W bufs @12288,16384 (40 KB total)
    // Ep (128x136 = 17408) aliases the buffer region after the loop.
    __shared__ __align__(16) short SH[20480];
    int d = blockIdx.x;
    int wg = (d & 7) * 192 + (d >> 3);     // bijective XCD chunk remap (1536 % 8 == 0)
    int m0 = (wg % 3) * 128;               // channel tile (n-side)
    int tx = wg / 3;                       // spatial tile
    int pid0 = tx * 2;
    int b  = blockIdx.z;
    int tid = threadIdx.x;
    int lane = tid & 63, w = tid >> 6;
    int wr = w >> 1, wc = w & 1;           // wr = pat, wc = ch-half
    int lm = lane & 15, quad = lane >> 4;

    const short* Xbase = Xt + ((size_t)b * HW + (size_t)pid0 * 64) * DIM;

    f32x4 acc[4][4];
#pragma unroll
    for (int i = 0; i < 4; ++i)
#pragma unroll
        for (int j = 0; j < 4; ++j) acc[i][j] = 0.f;

    int grow = tid >> 2, gseg = tid & 3;           // staging: row, 16B segment
    // prologue: X(0) -> X0, W(0) -> W0
#pragma unroll
    for (int q = 0; q < 2; ++q) {
        int G = q * 256 + tid;
        int row = grow + q * 64;
        int col = ((gseg ^ ((row >> 1) & 3)) << 3);
        gl_lds16(Xbase + (size_t)row * DIM + col, SH + G * 8);
        gl_lds16(W + (size_t)(m0 + row) * DIM + col, SH + 12288 + G * 8);
    }

    int fsw = (lm >> 1) & 3;                       // fragment-read swizzle
#pragma unroll
    for (int kc = 0; kc < 12; ++kc) {
        if (kc < 11) {                             // issue-early: next X tile
            int k0 = (kc + 1) * 32;
            short* xb = SH + ((kc + 1) % 3) * 4096;
#pragma unroll
            for (int q = 0; q < 2; ++q) {
                int G = q * 256 + tid;
                int row = grow + q * 64;
                int col = k0 + ((gseg ^ ((row >> 1) & 3)) << 3);
                gl_lds16(Xbase + (size_t)row * DIM + col, xb + G * 8);
            }
            asm volatile("s_waitcnt vmcnt(2)" ::: "memory");
        } else {
            asm volatile("s_waitcnt vmcnt(0)" ::: "memory");
        }
        __builtin_amdgcn_s_barrier();
        asm volatile("" ::: "memory");
        if (kc < 11) {                             // post-barrier: next W tile (2-buf safe)
            int k0 = (kc + 1) * 32;
            short* wb = SH + 12288 + ((kc + 1) & 1) * 4096;
#pragma unroll
            for (int q = 0; q < 2; ++q) {
                int G = q * 256 + tid;
                int row = grow + q * 64;
                int col = k0 + ((gseg ^ ((row >> 1) & 3)) << 3);
                gl_lds16(W + (size_t)(m0 + row) * DIM + col, wb + G * 8);
            }
        }
        const short* Xs = SH + (kc % 3) * 4096;
        const short* Ws = SH + 12288 + (kc & 1) * 4096;
        int csw = ((quad ^ fsw) << 3);
        bf16x8 af[4], bfr[4];
#pragma unroll
        for (int i = 0; i < 4; ++i)
            af[i] = __builtin_bit_cast(bf16x8, *(const s16x8*)&Xs[(wr * 64 + i * 16 + lm) * 32 + csw]);
#pragma unroll
        for (int j = 0; j < 4; ++j)
            bfr[j] = __builtin_bit_cast(bf16x8, *(const s16x8*)&Ws[(wc * 64 + j * 16 + lm) * 32 + csw]);
        __builtin_amdgcn_s_setprio(1);
#pragma unroll
        for (int i = 0; i < 4; ++i)
#pragma unroll
            for (int j = 0; j < 4; ++j)
                acc[i][j] = __builtin_amdgcn_mfma_f32_16x16x32_bf16(af[i], bfr[j], acc[i][j], 0, 0, 0);
        __builtin_amdgcn_s_setprio(0);
    }
    __syncthreads();   // buffers dead; Ep may alias

    // R fragments -> registers (L2-hot 8 KB table; epilogue-only liveness).
    // rfr[i][ks] = R[i*16+lm][ks*32 + quad*8 .. +8] — identical values to the
    // old swizzled-LDS path.
    s16x8 rfr[4][2];
#pragma unroll
    for (int i = 0; i < 4; ++i)
#pragma unroll
        for (int ks = 0; ks < 2; ++ks)
            rfr[i][ks] = *(const s16x8*)&Rb[(i * 16 + lm) * 64 + ks * 32 + quad * 8];

    // ---- E: C[pos][ch] -> Ep[ch][pat*64+uv], packed b64. Quadrant-local.
#pragma unroll
    for (int i = 0; i < 4; ++i)
#pragma unroll
        for (int j = 0; j < 4; ++j) {
            s16x4 v4;
#pragma unroll
            for (int r = 0; r < 4; ++r) v4[r] = f2b(acc[i][j][r]);
            *(s16x4*)&SH[(wc * 64 + j * 16 + lm) * 136 + wr * 64 + i * 16 + quad * 4] = v4;
        }

    // ---- stage 1: C1[j][ch] = sum_uv R[j][uv] * Ep[ch][uv]  (pat = wr)
    f32x4 acc2[4][4];
#pragma unroll
    for (int i = 0; i < 4; ++i)
#pragma unroll
        for (int j = 0; j < 4; ++j) acc2[i][j] = 0.f;
#pragma unroll
    for (int ks = 0; ks < 2; ++ks) {
        bf16x8 bfr[4];
#pragma unroll
        for (int j = 0; j < 4; ++j)
            bfr[j] = __builtin_bit_cast(bf16x8,
                *(const s16x8*)&SH[(wc * 64 + j * 16 + lm) * 136 + wr * 64 + ks * 32 + quad * 8]);
#pragma unroll
        for (int i = 0; i < 4; ++i)
#pragma unroll
            for (int j = 0; j < 4; ++j)
                acc2[i][j] = __builtin_amdgcn_mfma_f32_16x16x32_bf16(
                    __builtin_bit_cast(bf16x8, rfr[i][ks]), bfr[j], acc2[i][j], 0, 0, 0);
    }
    // scale by Dtc[ch][j] and write Ep2[ch][pat*64 + j], packed b64
#pragma unroll
    for (int i = 0; i < 4; ++i)
#pragma unroll
        for (int j2 = 0; j2 < 4; ++j2) {
            float4 dv = *(const float4*)&Dtc[(size_t)(m0 + wc * 64 + j2 * 16 + lm) * 64 + i * 16 + quad * 4];
            s16x4 v4;
            v4[0] = f2b(acc2[i][j2][0] * dv.x);
            v4[1] = f2b(acc2[i][j2][1] * dv.y);
            v4[2] = f2b(acc2[i][j2][2] * dv.z);
            v4[3] = f2b(acc2[i][j2][3] * dv.w);
            *(s16x4*)&SH[(wc * 64 + j2 * 16 + lm) * 136 + wr * 64 + i * 16 + quad * 4] = v4;
        }

    // ---- stage 2: C2[u][ch] = sum_j R[u][j] * Ep2[ch][j]
    f32x4 acc3[4][4];
#pragma unroll
    for (int i = 0; i < 4; ++i)
#pragma unroll
        for (int j = 0; j < 4; ++j) acc3[i][j] = 0.f;
#pragma unroll
    for (int ks = 0; ks < 2; ++ks) {
        bf16x8 bfr[4];
#pragma unroll
        for (int j = 0; j < 4; ++j)
            bfr[j] = __builtin_bit_cast(bf16x8,
                *(const s16x8*)&SH[(wc * 64 + j * 16 + lm) * 136 + wr * 64 + ks * 32 + quad * 8]);
#pragma unroll
        for (int i = 0; i < 4; ++i)
#pragma unroll
            for (int j = 0; j < 4; ++j)
                acc3[i][j] = __builtin_amdgcn_mfma_f32_16x16x32_bf16(
                    __builtin_bit_cast(bf16x8, rfr[i][ks]), bfr[j], acc3[i][j], 0, 0, 0);
    }
#pragma unroll
    for (int i = 0; i < 4; ++i)
#pragma unroll
        for (int j2 = 0; j2 < 4; ++j2) {
            s16x4 v4;
#pragma unroll
            for (int r = 0; r < 4; ++r) v4[r] = f2b(acc3[i][j2][r]);
            *(s16x4*)&SH[(wc * 64 + j2 * 16 + lm) * 136 + wr * 64 + i * 16 + quad * 4] = v4;
        }
    __syncthreads();   // write-out reads all rows
    // patch-major write: T[b][ch][pid][uv]
#pragma unroll
    for (int kq = 0; kq < 8; ++kq) {
        int idx = kq * 256 + tid;
        int row = idx >> 4, seg = idx & 15;
        s16x8 vv = *(const s16x8*)&SH[row * 136 + seg * 8];
        *(s16x8*)&T[(((size_t)(b * HID + m0 + row)) << 16) + pid0 * 64 + seg * 8] = vv;
    }
}

// ---------------------------------------------------------------------------
// Fused depthwise 3x3 + gelu-gate + transpose: T PATCH-MAJOR -> Gt k-blocked
// Gt: [b][kseg=24][hw][8ch]. Conv reads = 3x ds_read_b128 (conflict-free).
// GELU via erf_fast. Ob rebuffer row stride 580 -> 2-way scatter (free).
// ---------------------------------------------------------------------------
__global__ __launch_bounds__(256) void k_dwgt(const short* __restrict__ Y,
                                              const float* __restrict__ Wdw,
                                              short* __restrict__ Gt) {
    int bz = blockIdx.z;                 // b*24 + cg
    int b  = bz / 24;
    int cg = bz % 24;
    int c0 = cg * 8;
    int h0 = blockIdx.y * 16, w0 = blockIdx.x * 64;
    __shared__ __align__(16) short S[16][18][80];   // 46080 B; Ob aliases
    __shared__ float sw[16][9];
    int tid = threadIdx.x;
    if (tid < 144) {
        int p = tid / 9, j = tid % 9;
        int ch = (p < 8) ? (c0 + p) : (c0 + p - 8 + 192);
        sw[p][j] = Wdw[ch * 9 + j];
    }
    for (int t = tid; t < 2880; t += 256) {
        int v = t % 10, r = (t / 10) % 18, p = t / 180;
        int gh = h0 + r - 1;
        int gw = w0 + v * 8 - 8;
        int ch = (p < 8) ? (c0 + p) : (c0 + p - 8 + 192);
        s16x8 val = {0, 0, 0, 0, 0, 0, 0, 0};
        if (gh >= 0 && gh < 256 && gw >= 0 && gw <= 248) {
            int pid = ((gh >> 3) << 5) + (gw >> 3);
            val = *(const s16x8*)&Y[((size_t)(b * HID + ch) << 16) + (pid << 6) + ((gh & 7) << 3)];
        }
        *(s16x8*)&S[p][r][v * 8] = val;
    }
    __syncthreads();
    s16x8 ov[4];
#pragma unroll
    for (int it = 0; it < 4; ++it) {
        int idx = it * 256 + tid;
        int p = idx >> 7, run = idx & 127;
        int r = run >> 3, c8 = (run & 7) * 8;
        float z1[8], z2[8];
#pragma unroll
        for (int k = 0; k < 8; ++k) { z1[k] = 0.f; z2[k] = 0.f; }
#pragma unroll
        for (int i = 0; i < 3; ++i) {
            {
                s16x8 a0 = *(const s16x8*)&S[p][r + i][c8];
                s16x8 a1 = *(const s16x8*)&S[p][r + i][c8 + 8];
                s16x8 a2 = *(const s16x8*)&S[p][r + i][c8 + 16];
                float fv[10];
                fv[0] = b2f(a0[7]);
#pragma unroll
                for (int q = 1; q < 9; ++q) fv[q] = b2f(a1[q - 1]);
                fv[9] = b2f(a2[0]);
#pragma unroll
                for (int j = 0; j < 3; ++j) {
                    float wgt = sw[p][i * 3 + j];
#pragma unroll
                    for (int k = 0; k < 8; ++k) z1[k] += fv[k + j] * wgt;
                }
            }
            {
                s16x8 a0 = *(const s16x8*)&S[p + 8][r + i][c8];
                s16x8 a1 = *(const s16x8*)&S[p + 8][r + i][c8 + 8];
                s16x8 a2 = *(const s16x8*)&S[p + 8][r + i][c8 + 16];
                float fv[10];
                fv[0] = b2f(a0[7]);
#pragma unroll
                for (int q = 1; q < 9; ++q) fv[q] = b2f(a1[q - 1]);
                fv[9] = b2f(a2[0]);
#pragma unroll
                for (int j = 0; j < 3; ++j) {
                    float wgt = sw[p + 8][i * 3 + j];
#pragma unroll
                    for (int k = 0; k < 8; ++k) z2[k] += fv[k + j] * wgt;
                }
            }
        }
#pragma unroll
        for (int k = 0; k < 8; ++k) {
            float g = 0.5f * z1[k] * (1.f + erf_fast(z1[k] * 0.70710678118654752f));
            ov[it][k] = f2b(g * z2[k]);
        }
    }
    __syncthreads();
    // Ob layout: rows of stride 580 shorts; within row: pos_cl*9 + ch.
    short* Ob = (short*)S;
#pragma unroll
    for (int it = 0; it < 4; ++it) {
        int idx = it * 256 + tid;
        int p = idx >> 7, run = idx & 127;
        int rr = run >> 3, cb = (run & 7) * 8;
#pragma unroll
        for (int k = 0; k < 8; ++k)
            Ob[rr * 580 + (cb + k) * 9 + p] = ov[it][k];
    }
    __syncthreads();
    short* Gb = Gt + (((size_t)(b * 24 + cg)) << 16) * 8;
#pragma unroll
    for (int it = 0; it < 4; ++it) {
        int pos = it * 256 + tid;
        int r = pos >> 6, cl = pos & 63;
        s16x8 v;
#pragma unroll
        for (int k = 0; k < 8; ++k) v[k] = Ob[r * 580 + cl * 9 + k];
        *(s16x8*)&Gb[(size_t)(((h0 + r) << 8) + w0 + cl) * 8] = v;
    }
}

// ---------------------------------------------------------------------------
// MFMA bf16 GEMM2, counted-vmcnt pipeline: B (Gt, streaming) = 3 buffers
// pre-barrier; A (wbout, L2-hot) = 2 buffers post-barrier. LDS 40KB.
// C-write repacked through LDS (row pad 132 fp32, 2-way = free) into
// dwordx4 coalesced stores: 8 per thread vs 64 scalar dword.
// ---------------------------------------------------------------------------
__global__ __launch_bounds__(256) void k_gemm_bf16(const short* __restrict__ A,
                                                   const short* __restrict__ Bt,
                                                   float* __restrict__ C,
                                                   int N, int K) {
    // shorts: B bufs @0,4096,8192 | A bufs @12288,16384; Px (fp32 64x132) aliases
    __shared__ __align__(16) short SH[20480];
    const short* Bz = Bt + (size_t)blockIdx.z * (size_t)N * K;
    float* Cz = C + (size_t)blockIdx.z * (size_t)384 * N;
    int d = blockIdx.x;
    int wg = (d & 7) * 192 + (d >> 3);     // bijective XCD chunk remap
    int m0 = (wg % 3) * 128;
    int n0 = (wg / 3) * 128;
    int tid = threadIdx.x;
    int lane = tid & 63, w = tid >> 6;
    int wr = w >> 1, wc = w & 1;
    int lm = lane & 15, quad = lane >> 4;

    f32x4 acc[4][4];
#pragma unroll
    for (int i = 0; i < 4; ++i)
#pragma unroll
        for (int j = 0; j < 4; ++j) acc[i][j] = 0.f;

    int grow = tid >> 2, gseg = tid & 3;
    // prologue: B(0) -> B0, A(0) -> A0
#pragma unroll
    for (int q = 0; q < 2; ++q) {
        int row = grow + q * 64;
        int G = q * 256 + tid;
        int sg = gseg ^ ((row >> 1) & 3);
        gl_lds16(Bz + ((size_t)sg * HW + n0 + row) * 8, SH + G * 8);
        gl_lds16(A + (size_t)(m0 + row) * K + (sg << 3), SH + 12288 + G * 8);
    }

    int fsw = (lm >> 1) & 3;
#pragma unroll
    for (int kc = 0; kc < 6; ++kc) {
        if (kc < 5) {                              // issue-early: next B tile
            int k0 = (kc + 1) * 32;
            short* bb = SH + ((kc + 1) % 3) * 4096;
#pragma unroll
            for (int q = 0; q < 2; ++q) {
                int row = grow + q * 64;
                int G = q * 256 + tid;
                int sg = gseg ^ ((row >> 1) & 3);
                gl_lds16(Bz + ((size_t)((k0 >> 3) + sg) * HW + n0 + row) * 8, bb + G * 8);
            }
            asm volatile("s_waitcnt vmcnt(2)" ::: "memory");
        } else {
            asm volatile("s_waitcnt vmcnt(0)" ::: "memory");
        }
        __builtin_amdgcn_s_barrier();
        asm volatile("" ::: "memory");
        if (kc < 5) {                              // post-barrier: next A tile (2-buf safe)
            int k0 = (kc + 1) * 32;
            short* ab = SH + 12288 + ((kc + 1) & 1) * 4096;
#pragma unroll
            for (int q = 0; q < 2; ++q) {
                int row = grow + q * 64;
                int G = q * 256 + tid;
                int sg = gseg ^ ((row >> 1) & 3);
                gl_lds16(A + (size_t)(m0 + row) * K + k0 + (sg << 3), ab + G * 8);
            }
        }
        const short* Bs = SH + (kc % 3) * 4096;
        const short* As = SH + 12288 + (kc & 1) * 4096;
        int csw = ((quad ^ fsw) << 3);
        bf16x8 af[4], bfr[4];
#pragma unroll
        for (int i = 0; i < 4; ++i)
            af[i] = __builtin_bit_cast(bf16x8, *(const s16x8*)&As[(wr * 64 + i * 16 + lm) * 32 + csw]);
#pragma unroll
        for (int j = 0; j < 4; ++j)
            bfr[j] = __builtin_bit_cast(bf16x8, *(const s16x8*)&Bs[(wc * 64 + j * 16 + lm) * 32 + csw]);
        __builtin_amdgcn_s_setprio(1);
#pragma unroll
        for (int i = 0; i < 4; ++i)
#pragma unroll
            for (int j = 0; j < 4; ++j)
                acc[i][j] = __builtin_amdgcn_mfma_f32_16x16x32_bf16(af[i], bfr[j], acc[i][j], 0, 0, 0);
        __builtin_amdgcn_s_setprio(0);
    }
    // ---- vectorized C-write: 2 half-tiles (64 rows) through LDS fp32 repack
    __syncthreads();
    float* Px = (float*)SH;
#pragma unroll
    for (int h = 0; h < 2; ++h) {
        if (wr == h) {
#pragma unroll
            for (int i = 0; i < 4; ++i)
#pragma unroll
                for (int j = 0; j < 4; ++j)
#pragma unroll
                    for (int r = 0; r < 4; ++r)
                        Px[(i * 16 + quad * 4 + r) * 132 + wc * 64 + j * 16 + lm] = acc[i][j][r];
        }
        __syncthreads();
#pragma unroll
        for (int kq = 0; kq < 8; ++kq) {
            int idx = kq * 256 + tid;
            int row = idx >> 5, c4 = idx & 31;
            float4 v = *(const float4*)&Px[row * 132 + c4 * 4];
            *(float4*)&Cz[(size_t)(m0 + h * 64 + row) * N + n0 + c4 * 4] = v;
        }
        __syncthreads();
    }
}

// ---------------------------------------------------------------------------
extern "C" void kernel_launch(void* const* d_in, const int* in_sizes, int n_in,
                              void* d_out, int out_size, void* d_ws, size_t ws_size,
                              hipStream_t stream) {
    const float* x     = (const float*)d_in[0];
    const float* ff    = (const float*)d_in[1];
    const float* w_in  = (const float*)d_in[2];
    const float* w_dw  = (const float*)d_in[3];
    const float* w_out = (const float*)d_in[4];
    float* out = (float*)d_out;

    char* ws = (char*)d_ws;
    float* Dtc  = (float*)ws;                                    // 98304 B
    short* wbin = (short*)(ws + 98304);                          // 294912 B
    short* wbout = (short*)(ws + 393216);                        // 147456 B
    short* Rbuf = (short*)(ws + 540672);                         // 8192 B
    short* bufA = (short*)(ws + 548864);                         // 100663296 B: Xt, then Gt
    short* bufB = (short*)(ws + 548864 + (size_t)100663296);     // 100663296 B: T (patch-major)
    short* Gt = bufA;

    // x -> Xt bf16 patch-major (+ absorbed prep: wbin/wbout/Dtc/Rb)
    k_cvtx<<<dim3(HW / 64, DIM / 64, BB), 256, 0, stream>>>(x, bufA, w_in, w_out, ff,
                                                            wbin, wbout, Dtc, Rbuf);

    // fused GEMM1 + Hartley circular conv -> T bf16 patch-major
    k_gemm1c<<<dim3(1536, 1, BB), 256, 0, stream>>>(wbin, bufA, Rbuf, Dtc, bufB);

    // fused depthwise 3x3 + gelu-gate + transpose -> Gt k-blocked (bufA; Xt dead)
    k_dwgt<<<dim3(4, 16, BB * 24), 256, 0, stream>>>(bufB, w_dw, Gt);

    // GEMM2: out = w_out @ g  (M=384, N=65536/batch, K=192)
    k_gemm_bf16<<<dim3(1536, 1, BB), 256, 0, stream>>>(wbout, Gt, out, HW, 192);
}

// Round 15
// 529.958 us; speedup vs baseline: 1.0270x; 1.0270x over previous
//
#include <hip/hip_runtime.h>
#include <hip/hip_bf16.h>
#include <math.h>

#define BB 2
#define DIM 384
#define HID 384
#define HW 65536

typedef short s16x8 __attribute__((ext_vector_type(8)));
typedef short s16x4 __attribute__((ext_vector_type(4)));
typedef __bf16 bf16x8 __attribute__((ext_vector_type(8)));
typedef float f32x4 __attribute__((ext_vector_type(4)));

__device__ inline short f2b(float f) {
    __hip_bfloat16 h = __float2bfloat16(f);
    return __builtin_bit_cast(short, h);
}
__device__ inline float b2f(short s) {
    return __bfloat162float(__builtin_bit_cast(__hip_bfloat16, s));
}

// Abramowitz-Stegun 7.1.26 erf approximation, |err| <= 1.5e-7 absolute.
__device__ inline float erf_fast(float x) {
    float ax = fabsf(x);
    float t = __builtin_amdgcn_rcpf(fmaf(0.3275911f, ax, 1.f));
    float p = fmaf(t, 1.061405429f, -1.453152027f);
    p = fmaf(t, p, 1.421413741f);
    p = fmaf(t, p, -0.284496736f);
    p = fmaf(t, p, 0.254829592f);
    p = p * t;
    float e = __expf(-ax * ax);
    float r = fmaf(-p, e, 1.f);
    return copysignf(r, x);
}

__device__ inline void gl_lds16(const short* g, short* l) {
    __builtin_amdgcn_global_load_lds(
        (const __attribute__((address_space(1))) unsigned int*)g,
        (__attribute__((address_space(3))) unsigned int*)l, 16, 0, 0);
}

// ---------------------------------------------------------------------------
// x [b][c][hw] fp32 -> Xt PATCH-MAJOR [b][pid*64+uv][384] bf16.
// Also absorbs the prep work (wbin/wbout cvt, Dtc, Rb) in its first 976
// (y==0,z==0) blocks — 249856 = 976*256 items exactly; saves a launch.
// ---------------------------------------------------------------------------
__global__ __launch_bounds__(256) void k_cvtx(const float* __restrict__ X, short* __restrict__ Xt,
                                              const float* __restrict__ w_in,
                                              const float* __restrict__ w_out,
                                              const float* __restrict__ F,
                                              short* __restrict__ wbin, short* __restrict__ wbout,
                                              float* __restrict__ Dtc, short* __restrict__ Rb) {
    int hw0 = blockIdx.x * 64, c0 = blockIdx.y * 64, b = blockIdx.z;
    __shared__ __align__(16) short S[64 * 64];
    int t = threadIdx.x;
    if (blockIdx.y == 0 && blockIdx.z == 0 && blockIdx.x < 976) {
        int i = blockIdx.x * 256 + t;
        if (i < 147456) { wbin[i] = f2b(w_in[i]); }
        else if ((i -= 147456) < 73728) { wbout[i] = f2b(w_out[i]); }
        else if ((i -= 73728) < 24576) {
            int c = i >> 6, j = i & 63;
            int a = j >> 3, q = j & 7;
            float d;
            if (q >= 1 && q <= 3)
                d = F[c * 40 + a * 5 + q];
            else if (q >= 5)
                d = F[c * 40 + ((8 - a) & 7) * 5 + (8 - q)];
            else
                d = 0.5f * (F[c * 40 + a * 5 + q] + F[c * 40 + ((8 - a) & 7) * 5 + q]);
            Dtc[i] = d * (1.f / 64.f);
        } else {
            i -= 24576;   // < 4096
            int j = i >> 6, k = i & 63;
            const float cas[8] = {1.f, 1.41421356237f, 1.f, 0.f, -1.f, -1.41421356237f, -1.f, 0.f};
            int tt = ((j >> 3) * (k >> 3) + (j & 7) * (k & 7)) & 7;
            Rb[i] = f2b(cas[tt]);
        }
    }
    const float* Xb = X + ((size_t)(b * DIM) << 16);
    short* Xtb = Xt + (size_t)b * HW * DIM;
#pragma unroll
    for (int p = 0; p < 2; ++p) {
        int row = p * 32 + (t >> 3), sb = t & 7;
        const float* src = &Xb[((size_t)(c0 + row) << 16) + hw0 + sb * 8];
        float4 a = *(const float4*)src;
        float4 bq = *(const float4*)(src + 4);
        s16x8 v;
        v[0] = f2b(a.x);  v[1] = f2b(a.y);  v[2] = f2b(a.z);  v[3] = f2b(a.w);
        v[4] = f2b(bq.x); v[5] = f2b(bq.y); v[6] = f2b(bq.z); v[7] = f2b(bq.w);
        *(s16x8*)&S[row * 64 + ((sb ^ (row >> 3)) << 3)] = v;
    }
    __syncthreads();
    int h = hw0 >> 8, wb0 = hw0 & 255;
#pragma unroll
    for (int p = 0; p < 2; ++p) {
        int row = p * 32 + (t >> 3), ch = t & 7;
        s16x8 v;
#pragma unroll
        for (int j = 0; j < 8; ++j)
            v[j] = S[(ch * 8 + j) * 64 + (row ^ (ch << 3))];
        int wv = wb0 + row;
        int rowp = (((h >> 3) << 5) + (wv >> 3)) * 64 + ((h & 7) << 3) + (wv & 7);
        *(s16x8*)&Xtb[(size_t)rowp * DIM + c0 + ch * 8] = v;
    }
}

// ---------------------------------------------------------------------------
// Fused GEMM1 + Hartley circular conv. Counted-vmcnt pipeline:
// X (streaming) = 3 buffers issued BEFORE the barrier; W (L2-hot weights) =
// 2 buffers issued AFTER the barrier (race-free by barrier ordering).
// One s_barrier per chunk; vmcnt(2) in steady state. Rs in LDS (R10/R14
// lesson: both reg-R variants regressed — 48 KB + Rs-in-LDS is the optimum).
// ---------------------------------------------------------------------------
__global__ __launch_bounds__(256) void k_gemm1c(const short* __restrict__ W,
                                                const short* __restrict__ Xt,
                                                const short* __restrict__ Rb,
                                                const float* __restrict__ Dtc,
                                                short* __restrict__ T) {
    // shorts: X bufs @0,4096,8192 | W bufs @12288,16384 | Rs @20480
    // Ep (128x136 = 17408) aliases the buffer region after the loop.
    __shared__ __align__(16) short SH[24576];
    short* Rs = SH + 20480;
    int d = blockIdx.x;
    int wg = (d & 7) * 192 + (d >> 3);     // bijective XCD chunk remap (1536 % 8 == 0)
    int m0 = (wg % 3) * 128;               // channel tile (n-side)
    int tx = wg / 3;                       // spatial tile
    int pid0 = tx * 2;
    int b  = blockIdx.z;
    int tid = threadIdx.x;
    int lane = tid & 63, w = tid >> 6;
    int wr = w >> 1, wc = w & 1;           // wr = pat, wc = ch-half
    int lm = lane & 15, quad = lane >> 4;

    // stage Hartley basis R (swizzled source -> linear LDS dest)
    {
        int j0 = tid >> 3, kb0 = tid & 7;
        gl_lds16(Rb + j0 * 64 + ((kb0 ^ (j0 & 7)) << 3), Rs + tid * 8);
        int t2 = tid + 256;
        int j1 = t2 >> 3, kb1 = t2 & 7;
        gl_lds16(Rb + j1 * 64 + ((kb1 ^ (j1 & 7)) << 3), Rs + t2 * 8);
    }

    const short* Xbase = Xt + ((size_t)b * HW + (size_t)pid0 * 64) * DIM;

    f32x4 acc[4][4];
#pragma unroll
    for (int i = 0; i < 4; ++i)
#pragma unroll
        for (int j = 0; j < 4; ++j) acc[i][j] = 0.f;

    int grow = tid >> 2, gseg = tid & 3;           // staging: row, 16B segment
    // prologue: X(0) -> X0, W(0) -> W0
#pragma unroll
    for (int q = 0; q < 2; ++q) {
        int G = q * 256 + tid;
        int row = grow + q * 64;
        int col = ((gseg ^ ((row >> 1) & 3)) << 3);
        gl_lds16(Xbase + (size_t)row * DIM + col, SH + G * 8);
        gl_lds16(W + (size_t)(m0 + row) * DIM + col, SH + 12288 + G * 8);
    }

    int fsw = (lm >> 1) & 3;                       // fragment-read swizzle
#pragma unroll
    for (int kc = 0; kc < 12; ++kc) {
        if (kc < 11) {                             // issue-early: next X tile
            int k0 = (kc + 1) * 32;
            short* xb = SH + ((kc + 1) % 3) * 4096;
#pragma unroll
            for (int q = 0; q < 2; ++q) {
                int G = q * 256 + tid;
                int row = grow + q * 64;
                int col = k0 + ((gseg ^ ((row >> 1) & 3)) << 3);
                gl_lds16(Xbase + (size_t)row * DIM + col, xb + G * 8);
            }
            asm volatile("s_waitcnt vmcnt(2)" ::: "memory");
        } else {
            asm volatile("s_waitcnt vmcnt(0)" ::: "memory");
        }
        __builtin_amdgcn_s_barrier();
        asm volatile("" ::: "memory");
        if (kc < 11) {                             // post-barrier: next W tile (2-buf safe)
            int k0 = (kc + 1) * 32;
            short* wb = SH + 12288 + ((kc + 1) & 1) * 4096;
#pragma unroll
            for (int q = 0; q < 2; ++q) {
                int G = q * 256 + tid;
                int row = grow + q * 64;
                int col = k0 + ((gseg ^ ((row >> 1) & 3)) << 3);
                gl_lds16(W + (size_t)(m0 + row) * DIM + col, wb + G * 8);
            }
        }
        const short* Xs = SH + (kc % 3) * 4096;
        const short* Ws = SH + 12288 + (kc & 1) * 4096;
        int csw = ((quad ^ fsw) << 3);
        bf16x8 af[4], bfr[4];
#pragma unroll
        for (int i = 0; i < 4; ++i)
            af[i] = __builtin_bit_cast(bf16x8, *(const s16x8*)&Xs[(wr * 64 + i * 16 + lm) * 32 + csw]);
#pragma unroll
        for (int j = 0; j < 4; ++j)
            bfr[j] = __builtin_bit_cast(bf16x8, *(const s16x8*)&Ws[(wc * 64 + j * 16 + lm) * 32 + csw]);
        __builtin_amdgcn_s_setprio(1);
#pragma unroll
        for (int i = 0; i < 4; ++i)
#pragma unroll
            for (int j = 0; j < 4; ++j)
                acc[i][j] = __builtin_amdgcn_mfma_f32_16x16x32_bf16(af[i], bfr[j], acc[i][j], 0, 0, 0);
        __builtin_amdgcn_s_setprio(0);
    }
    __syncthreads();   // buffers dead; Ep may alias

    // ---- E: C[pos][ch] -> Ep[ch][pat*64+uv], packed b64. Quadrant-local.
#pragma unroll
    for (int i = 0; i < 4; ++i)
#pragma unroll
        for (int j = 0; j < 4; ++j) {
            s16x4 v4;
#pragma unroll
            for (int r = 0; r < 4; ++r) v4[r] = f2b(acc[i][j][r]);
            *(s16x4*)&SH[(wc * 64 + j * 16 + lm) * 136 + wr * 64 + i * 16 + quad * 4] = v4;
        }

    // ---- stage 1: C1[j][ch] = sum_uv R[j][uv] * Ep[ch][uv]  (pat = wr)
    f32x4 acc2[4][4];
#pragma unroll
    for (int i = 0; i < 4; ++i)
#pragma unroll
        for (int j = 0; j < 4; ++j) acc2[i][j] = 0.f;
#pragma unroll
    for (int ks = 0; ks < 2; ++ks) {
        int csw = (((ks * 4 + quad) ^ (lm & 7)) << 3);
        bf16x8 af[4], bfr[4];
#pragma unroll
        for (int i = 0; i < 4; ++i)
            af[i] = __builtin_bit_cast(bf16x8, *(const s16x8*)&Rs[(i * 16 + lm) * 64 + csw]);
#pragma unroll
        for (int j = 0; j < 4; ++j)
            bfr[j] = __builtin_bit_cast(bf16x8,
                *(const s16x8*)&SH[(wc * 64 + j * 16 + lm) * 136 + wr * 64 + ks * 32 + quad * 8]);
#pragma unroll
        for (int i = 0; i < 4; ++i)
#pragma unroll
            for (int j = 0; j < 4; ++j)
                acc2[i][j] = __builtin_amdgcn_mfma_f32_16x16x32_bf16(af[i], bfr[j], acc2[i][j], 0, 0, 0);
    }
    // scale by Dtc[ch][j] and write Ep2[ch][pat*64 + j], packed b64
#pragma unroll
    for (int i = 0; i < 4; ++i)
#pragma unroll
        for (int j2 = 0; j2 < 4; ++j2) {
            float4 dv = *(const float4*)&Dtc[(size_t)(m0 + wc * 64 + j2 * 16 + lm) * 64 + i * 16 + quad * 4];
            s16x4 v4;
            v4[0] = f2b(acc2[i][j2][0] * dv.x);
            v4[1] = f2b(acc2[i][j2][1] * dv.y);
            v4[2] = f2b(acc2[i][j2][2] * dv.z);
            v4[3] = f2b(acc2[i][j2][3] * dv.w);
            *(s16x4*)&SH[(wc * 64 + j2 * 16 + lm) * 136 + wr * 64 + i * 16 + quad * 4] = v4;
        }

    // ---- stage 2: C2[u][ch] = sum_j R[u][j] * Ep2[ch][j]
    f32x4 acc3[4][4];
#pragma unroll
    for (int i = 0; i < 4; ++i)
#pragma unroll
        for (int j = 0; j < 4; ++j) acc3[i][j] = 0.f;
#pragma unroll
    for (int ks = 0; ks < 2; ++ks) {
        int csw = (((ks * 4 + quad) ^ (lm & 7)) << 3);
        bf16x8 af[4], bfr[4];
#pragma unroll
        for (int i = 0; i < 4; ++i)
            af[i] = __builtin_bit_cast(bf16x8, *(const s16x8*)&Rs[(i * 16 + lm) * 64 + csw]);
#pragma unroll
        for (int j = 0; j < 4; ++j)
            bfr[j] = __builtin_bit_cast(bf16x8,
                *(const s16x8*)&SH[(wc * 64 + j * 16 + lm) * 136 + wr * 64 + ks * 32 + quad * 8]);
#pragma unroll
        for (int i = 0; i < 4; ++i)
#pragma unroll
            for (int j = 0; j < 4; ++j)
                acc3[i][j] = __builtin_amdgcn_mfma_f32_16x16x32_bf16(af[i], bfr[j], acc3[i][j], 0, 0, 0);
    }
#pragma unroll
    for (int i = 0; i < 4; ++i)
#pragma unroll
        for (int j2 = 0; j2 < 4; ++j2) {
            s16x4 v4;
#pragma unroll
            for (int r = 0; r < 4; ++r) v4[r] = f2b(acc3[i][j2][r]);
            *(s16x4*)&SH[(wc * 64 + j2 * 16 + lm) * 136 + wr * 64 + i * 16 + quad * 4] = v4;
        }
    __syncthreads();   // write-out reads all rows
    // patch-major write: T[b][ch][pid][uv]
#pragma unroll
    for (int kq = 0; kq < 8; ++kq) {
        int idx = kq * 256 + tid;
        int row = idx >> 4, seg = idx & 15;
        s16x8 vv = *(const s16x8*)&SH[row * 136 + seg * 8];
        *(s16x8*)&T[(((size_t)(b * HID + m0 + row)) << 16) + pid0 * 64 + seg * 8] = vv;
    }
}

// ---------------------------------------------------------------------------
// Fused depthwise 3x3 + gelu-gate + transpose: T PATCH-MAJOR -> Gt k-blocked
// Gt: [b][kseg=24][hw][8ch]. Conv reads = 3x ds_read_b128 (conflict-free).
// GELU via erf_fast. Ob rebuffer row stride 580 -> 2-way scatter (free).
// ---------------------------------------------------------------------------
__global__ __launch_bounds__(256) void k_dwgt(const short* __restrict__ Y,
                                              const float* __restrict__ Wdw,
                                              short* __restrict__ Gt) {
    int bz = blockIdx.z;                 // b*24 + cg
    int b  = bz / 24;
    int cg = bz % 24;
    int c0 = cg * 8;
    int h0 = blockIdx.y * 16, w0 = blockIdx.x * 64;
    __shared__ __align__(16) short S[16][18][80];   // 46080 B; Ob aliases
    __shared__ float sw[16][9];
    int tid = threadIdx.x;
    if (tid < 144) {
        int p = tid / 9, j = tid % 9;
        int ch = (p < 8) ? (c0 + p) : (c0 + p - 8 + 192);
        sw[p][j] = Wdw[ch * 9 + j];
    }
    for (int t = tid; t < 2880; t += 256) {
        int v = t % 10, r = (t / 10) % 18, p = t / 180;
        int gh = h0 + r - 1;
        int gw = w0 + v * 8 - 8;
        int ch = (p < 8) ? (c0 + p) : (c0 + p - 8 + 192);
        s16x8 val = {0, 0, 0, 0, 0, 0, 0, 0};
        if (gh >= 0 && gh < 256 && gw >= 0 && gw <= 248) {
            int pid = ((gh >> 3) << 5) + (gw >> 3);
            val = *(const s16x8*)&Y[((size_t)(b * HID + ch) << 16) + (pid << 6) + ((gh & 7) << 3)];
        }
        *(s16x8*)&S[p][r][v * 8] = val;
    }
    __syncthreads();
    s16x8 ov[4];
#pragma unroll
    for (int it = 0; it < 4; ++it) {
        int idx = it * 256 + tid;
        int p = idx >> 7, run = idx & 127;
        int r = run >> 3, c8 = (run & 7) * 8;
        float z1[8], z2[8];
#pragma unroll
        for (int k = 0; k < 8; ++k) { z1[k] = 0.f; z2[k] = 0.f; }
#pragma unroll
        for (int i = 0; i < 3; ++i) {
            {
                s16x8 a0 = *(const s16x8*)&S[p][r + i][c8];
                s16x8 a1 = *(const s16x8*)&S[p][r + i][c8 + 8];
                s16x8 a2 = *(const s16x8*)&S[p][r + i][c8 + 16];
                float fv[10];
                fv[0] = b2f(a0[7]);
#pragma unroll
                for (int q = 1; q < 9; ++q) fv[q] = b2f(a1[q - 1]);
                fv[9] = b2f(a2[0]);
#pragma unroll
                for (int j = 0; j < 3; ++j) {
                    float wgt = sw[p][i * 3 + j];
#pragma unroll
                    for (int k = 0; k < 8; ++k) z1[k] += fv[k + j] * wgt;
                }
            }
            {
                s16x8 a0 = *(const s16x8*)&S[p + 8][r + i][c8];
                s16x8 a1 = *(const s16x8*)&S[p + 8][r + i][c8 + 8];
                s16x8 a2 = *(const s16x8*)&S[p + 8][r + i][c8 + 16];
                float fv[10];
                fv[0] = b2f(a0[7]);
#pragma unroll
                for (int q = 1; q < 9; ++q) fv[q] = b2f(a1[q - 1]);
                fv[9] = b2f(a2[0]);
#pragma unroll
                for (int j = 0; j < 3; ++j) {
                    float wgt = sw[p + 8][i * 3 + j];
#pragma unroll
                    for (int k = 0; k < 8; ++k) z2[k] += fv[k + j] * wgt;
                }
            }
        }
#pragma unroll
        for (int k = 0; k < 8; ++k) {
            float g = 0.5f * z1[k] * (1.f + erf_fast(z1[k] * 0.70710678118654752f));
            ov[it][k] = f2b(g * z2[k]);
        }
    }
    __syncthreads();
    // Ob layout: rows of stride 580 shorts; within row: pos_cl*9 + ch.
    short* Ob = (short*)S;
#pragma unroll
    for (int it = 0; it < 4; ++it) {
        int idx = it * 256 + tid;
        int p = idx >> 7, run = idx & 127;
        int rr = run >> 3, cb = (run & 7) * 8;
#pragma unroll
        for (int k = 0; k < 8; ++k)
            Ob[rr * 580 + (cb + k) * 9 + p] = ov[it][k];
    }
    __syncthreads();
    short* Gb = Gt + (((size_t)(b * 24 + cg)) << 16) * 8;
#pragma unroll
    for (int it = 0; it < 4; ++it) {
        int pos = it * 256 + tid;
        int r = pos >> 6, cl = pos & 63;
        s16x8 v;
#pragma unroll
        for (int k = 0; k < 8; ++k) v[k] = Ob[r * 580 + cl * 9 + k];
        *(s16x8*)&Gb[(size_t)(((h0 + r) << 8) + w0 + cl) * 8] = v;
    }
}

// ---------------------------------------------------------------------------
// MFMA bf16 GEMM2, counted-vmcnt pipeline: B (Gt, streaming) = 3 buffers
// pre-barrier; A (wbout, L2-hot) = 2 buffers post-barrier. LDS 40KB.
// C-write repacked through LDS (row pad 132 fp32, 2-way = free) into
// dwordx4 coalesced stores: 8 per thread vs 64 scalar dword.
// ---------------------------------------------------------------------------
__global__ __launch_bounds__(256) void k_gemm_bf16(const short* __restrict__ A,
                                                   const short* __restrict__ Bt,
                                                   float* __restrict__ C,
                                                   int N, int K) {
    // shorts: B bufs @0,4096,8192 | A bufs @12288,16384; Px (fp32 64x132) aliases
    __shared__ __align__(16) short SH[20480];
    const short* Bz = Bt + (size_t)blockIdx.z * (size_t)N * K;
    float* Cz = C + (size_t)blockIdx.z * (size_t)384 * N;
    int d = blockIdx.x;
    int wg = (d & 7) * 192 + (d >> 3);     // bijective XCD chunk remap
    int m0 = (wg % 3) * 128;
    int n0 = (wg / 3) * 128;
    int tid = threadIdx.x;
    int lane = tid & 63, w = tid >> 6;
    int wr = w >> 1, wc = w & 1;
    int lm = lane & 15, quad = lane >> 4;

    f32x4 acc[4][4];
#pragma unroll
    for (int i = 0; i < 4; ++i)
#pragma unroll
        for (int j = 0; j < 4; ++j) acc[i][j] = 0.f;

    int grow = tid >> 2, gseg = tid & 3;
    // prologue: B(0) -> B0, A(0) -> A0
#pragma unroll
    for (int q = 0; q < 2; ++q) {
        int row = grow + q * 64;
        int G = q * 256 + tid;
        int sg = gseg ^ ((row >> 1) & 3);
        gl_lds16(Bz + ((size_t)sg * HW + n0 + row) * 8, SH + G * 8);
        gl_lds16(A + (size_t)(m0 + row) * K + (sg << 3), SH + 12288 + G * 8);
    }

    int fsw = (lm >> 1) & 3;
#pragma unroll
    for (int kc = 0; kc < 6; ++kc) {
        if (kc < 5) {                              // issue-early: next B tile
            int k0 = (kc + 1) * 32;
            short* bb = SH + ((kc + 1) % 3) * 4096;
#pragma unroll
            for (int q = 0; q < 2; ++q) {
                int row = grow + q * 64;
                int G = q * 256 + tid;
                int sg = gseg ^ ((row >> 1) & 3);
                gl_lds16(Bz + ((size_t)((k0 >> 3) + sg) * HW + n0 + row) * 8, bb + G * 8);
            }
            asm volatile("s_waitcnt vmcnt(2)" ::: "memory");
        } else {
            asm volatile("s_waitcnt vmcnt(0)" ::: "memory");
        }
        __builtin_amdgcn_s_barrier();
        asm volatile("" ::: "memory");
        if (kc < 5) {                              // post-barrier: next A tile (2-buf safe)
            int k0 = (kc + 1) * 32;
            short* ab = SH + 12288 + ((kc + 1) & 1) * 4096;
#pragma unroll
            for (int q = 0; q < 2; ++q) {
                int row = grow + q * 64;
                int G = q * 256 + tid;
                int sg = gseg ^ ((row >> 1) & 3);
                gl_lds16(A + (size_t)(m0 + row) * K + k0 + (sg << 3), ab + G * 8);
            }
        }
        const short* Bs = SH + (kc % 3) * 4096;
        const short* As = SH + 12288 + (kc & 1) * 4096;
        int csw = ((quad ^ fsw) << 3);
        bf16x8 af[4], bfr[4];
#pragma unroll
        for (int i = 0; i < 4; ++i)
            af[i] = __builtin_bit_cast(bf16x8, *(const s16x8*)&As[(wr * 64 + i * 16 + lm) * 32 + csw]);
#pragma unroll
        for (int j = 0; j < 4; ++j)
            bfr[j] = __builtin_bit_cast(bf16x8, *(const s16x8*)&Bs[(wc * 64 + j * 16 + lm) * 32 + csw]);
        __builtin_amdgcn_s_setprio(1);
#pragma unroll
        for (int i = 0; i < 4; ++i)
#pragma unroll
            for (int j = 0; j < 4; ++j)
                acc[i][j] = __builtin_amdgcn_mfma_f32_16x16x32_bf16(af[i], bfr[j], acc[i][j], 0, 0, 0);
        __builtin_amdgcn_s_setprio(0);
    }
    // ---- vectorized C-write: 2 half-tiles (64 rows) through LDS fp32 repack
    __syncthreads();
    float* Px = (float*)SH;
#pragma unroll
    for (int h = 0; h < 2; ++h) {
        if (wr == h) {
#pragma unroll
            for (int i = 0; i < 4; ++i)
#pragma unroll
                for (int j = 0; j < 4; ++j)
#pragma unroll
                    for (int r = 0; r < 4; ++r)
                        Px[(i * 16 + quad * 4 + r) * 132 + wc * 64 + j * 16 + lm] = acc[i][j][r];
        }
        __syncthreads();
#pragma unroll
        for (int kq = 0; kq < 8; ++kq) {
            int idx = kq * 256 + tid;
            int row = idx >> 5, c4 = idx & 31;
            float4 v = *(const float4*)&Px[row * 132 + c4 * 4];
            *(float4*)&Cz[(size_t)(m0 + h * 64 + row) * N + n0 + c4 * 4] = v;
        }
        __syncthreads();
    }
}

// ---------------------------------------------------------------------------
extern "C" void kernel_launch(void* const* d_in, const int* in_sizes, int n_in,
                              void* d_out, int out_size, void* d_ws, size_t ws_size,
                              hipStream_t stream) {
    const float* x     = (const float*)d_in[0];
    const float* ff    = (const float*)d_in[1];
    const float* w_in  = (const float*)d_in[2];
    const float* w_dw  = (const float*)d_in[3];
    const float* w_out = (const float*)d_in[4];
    float* out = (float*)d_out;

    char* ws = (char*)d_ws;
    float* Dtc  = (float*)ws;                                    // 98304 B
    short* wbin = (short*)(ws + 98304);                          // 294912 B
    short* wbout = (short*)(ws + 393216);                        // 147456 B
    short* Rbuf = (short*)(ws + 540672);                         // 8192 B
    short* bufA = (short*)(ws + 548864);                         // 100663296 B: Xt, then Gt
    short* bufB = (short*)(ws + 548864 + (size_t)100663296);     // 100663296 B: T (patch-major)
    short* Gt = bufA;

    // x -> Xt bf16 patch-major (+ absorbed prep: wbin/wbout/Dtc/Rb)
    k_cvtx<<<dim3(HW / 64, DIM / 64, BB), 256, 0, stream>>>(x, bufA, w_in, w_out, ff,
                                                            wbin, wbout, Dtc, Rbuf);

    // fused GEMM1 + Hartley circular conv -> T bf16 patch-major
    k_gemm1c<<<dim3(1536, 1, BB), 256, 0, stream>>>(wbin, bufA, Rbuf, Dtc, bufB);

    // fused depthwise 3x3 + gelu-gate + transpose -> Gt k-blocked (bufA; Xt dead)
    k_dwgt<<<dim3(4, 16, BB * 24), 256, 0, stream>>>(bufB, w_dw, Gt);

    // GEMM2: out = w_out @ g  (M=384, N=65536/batch, K=192)
    k_gemm_bf16<<<dim3(1536, 1, BB), 256, 0, stream>>>(wbout, Gt, out, HW, 192);
}